// Round 9
// baseline (122.298 us; speedup 1.0000x reference)
//
#include <hip/hip_runtime.h>

#define B_SZ   4096
#define H_SZ   200
#define D_SZ   128
#define N_SZ   256
#define ROWS   (B_SZ * H_SZ)      // 819200
#define BM     64
#define TPB    8                  // tiles per block
#define RPB    (BM * TPB)         // 512 rows per block
#define NBLK   (ROWS / RPB)       // 1600

typedef _Float16 f16;
typedef __attribute__((ext_vector_type(2))) _Float16 f16x2;
typedef __attribute__((ext_vector_type(8))) _Float16 f16x8;
typedef __attribute__((ext_vector_type(4))) float f32x4;

union H8 { f16x8 v; f16x2 p[4]; uint4 u; };

__device__ __forceinline__ f16x2 pkrtz(float a, float b) {
    return __builtin_bit_cast(f16x2, __builtin_amdgcn_cvt_pkrtz(a, b));
}

// Kernel 0a: embed_history f32 -> f16 (RTZ pack), 8 elems/thread
__global__ __launch_bounds__(256) void cvt_eh(const float* __restrict__ src,
                                              uint4* __restrict__ dst, int n8) {
    int i = blockIdx.x * 256 + threadIdx.x;
    if (i >= n8) return;
    const f32x4* p = (const f32x4*)src + (size_t)i * 2;
    f32x4 a = p[0], b = p[1];
    uint4 o;
    o.x = __builtin_bit_cast(unsigned, pkrtz(a[0], a[1]));
    o.y = __builtin_bit_cast(unsigned, pkrtz(a[2], a[3]));
    o.z = __builtin_bit_cast(unsigned, pkrtz(b[0], b[1]));
    o.w = __builtin_bit_cast(unsigned, pkrtz(b[2], b[3]));
    dst[i] = o;
}

// Kernel 0b: W1 [128][256] f32 -> W1T/16 [256][128] f16
__global__ __launch_bounds__(256) void cvt_w1(const float* __restrict__ src,
                                              f16* __restrict__ dst) {
    int i = blockIdx.x * 256 + threadIdx.x;   // i = n*128 + d
    int n = i >> 7, d = i & 127;
    dst[i] = (f16)(src[d * N_SZ + n] * 0.0625f);
}

// Main: 512 thr = 8 waves arranged 2M x 4N.
// Wave (wr=wid>>2, wc=wid&3) owns rows [32wr,32wr+32) x n-cols [64wc,64wc+64).
// -> each wave reads only HALF the A-tile (af DS traffic halved vs 1Mx8N),
//    while keeping 8 waves/block for barrier-phase overlap.
__global__ __launch_bounds__(512, 3) void nais_main(
    const int* __restrict__ history, const int* __restrict__ target,
    const uint4* __restrict__ ehh, const float* __restrict__ et,
    const f16* __restrict__ w1t, const float* __restrict__ b1,
    const float* __restrict__ w2,
    float* __restrict__ a_out, float* __restrict__ dotd_out)
{
    __shared__ uint4 AbufV[2][BM * 256 / 16];  // 32 KB swizzled [64][128] f16 x2
    __shared__ float apart[2][4][BM];          // 2 KB (4 wc-planes)
    __shared__ f16   tgt_h[4][D_SZ];           // 1 KB (t * 16, f16)
    __shared__ int   tgt_i[4];

    const int tid  = threadIdx.x;
    const int wid  = tid >> 6;
    const int lane = tid & 63;
    const int lo   = lane & 15;
    const int hi   = lane >> 4;
    const int wr   = wid >> 2;       // row-half 0..1
    const int wc   = wid & 3;        // n-quarter 0..3
    const int row  = tid >> 3;
    const int seg  = tid & 7;
    const int blk  = blockIdx.x;
    const int b_base = (blk * RPB) / H_SZ;

    if (tid < 4) {
        int bb = b_base + tid;
        tgt_i[tid] = target[bb < B_SZ ? bb : (B_SZ - 1)];
    }
    __syncthreads();
    if (tid < 256) {   // preload 4 target rows as f16 * 16
        const int r4 = tid >> 6, j = (tid & 63) * 2;
        const float* src = et + (size_t)tgt_i[r4] * D_SZ + j;
        ((f16x2*)tgt_h)[tid] = pkrtz(src[0] * 16.f, src[1] * 16.f);
    }

    // W1T/16 fragments: wave's n-cols [64*wc, 64*wc+64)
    f16x8 wfrag[4][4];
    #pragma unroll
    for (int ni = 0; ni < 4; ++ni) {
        int n = 64 * wc + 16 * ni + lo;
        #pragma unroll
        for (int ki = 0; ki < 4; ++ki)
            wfrag[ki][ni] = *(const f16x8*)(w1t + (size_t)n * D_SZ + 32 * ki + 8 * hi);
    }
    // b1 / w2 per-lane: n = 64wc + 16ni + 4hi + r
    const int n0 = 64 * wc + 4 * hi;
    f32x4 b1v[4], w2v[4];
    #pragma unroll
    for (int ni = 0; ni < 4; ++ni) {
        b1v[ni] = *(const f32x4*)(b1 + n0 + 16 * ni);
        w2v[ni] = *(const f32x4*)(w2 + n0 + 16 * ni);
    }

    // gather pipeline prologue (16 f16 per thread per row)
    const int grow0 = blk * RPB + row;
    const int* hrow = history + grow0;
    int ih_cur = hrow[0];
    int ih_nxt = hrow[BM];
    uint4 hq0, hq1;
    {
        const uint4* p = ehh + (size_t)ih_cur * 16;
        hq0 = p[seg]; hq1 = p[8 + seg];
    }
    // incremental b_loc
    int b_loc = grow0 / H_SZ - b_base;
    int rem   = grow0 - (b_loc + b_base) * H_SZ;
    __syncthreads();   // tgt_h ready

    for (int t = 0; t < TPB; ++t) {
        char* Ab = (char*)AbufV[t & 1];
        const int gr = grow0 + t * BM;

        // ---- construct tile t (f16 packed) ----
        {
            H8 h1, h2, t1, t2, x1, x2;
            h1.u = hq0; h2.u = hq1;
            t1.v = *(const f16x8*)&tgt_h[b_loc][8 * seg];
            t2.v = *(const f16x8*)&tgt_h[b_loc][64 + 8 * seg];
            x1.v = h1.v * t1.v;        // 16*x, f16 packed
            x2.v = h2.v * t2.v;
            float s = 0.f;
            #pragma unroll
            for (int j = 0; j < 4; ++j) {
                s = __builtin_amdgcn_fdot2(h1.p[j], t1.p[j], s, false);
                s = __builtin_amdgcn_fdot2(h2.p[j], t2.p[j], s, false);
            }
            s += __shfl_xor(s, 1);
            s += __shfl_xor(s, 2);
            s += __shfl_xor(s, 4);
            if (seg == 0) dotd_out[gr] = s * 0.0625f;
            const unsigned sw = (unsigned)((row & 7) << 4);
            char* rb = Ab + row * 256;
            *(uint4*)(rb + (((unsigned)(16 * seg)) ^ sw))          = x1.u;
            *(uint4*)(rb + (128u + (((unsigned)(16 * seg)) ^ sw))) = x2.u;
        }
        __syncthreads();   // [single barrier per tile]

        // ---- prefetch next tile's gathers (hide under MFMA) ----
        if (t + 1 < TPB) {
            ih_cur = ih_nxt;
            if (t + 2 < TPB) ih_nxt = hrow[(t + 2) * BM];
            const uint4* p = ehh + (size_t)ih_cur * 16;
            hq0 = p[seg]; hq1 = p[8 + seg];
        }

        // ---- lagged reduction of tile t-1's apart (4 wc-planes) ----
        if (t > 0 && tid < BM) {
            const float* ap = &apart[(t - 1) & 1][0][tid];
            float a = ap[0] + ap[BM] + ap[2 * BM] + ap[3 * BM];
            a_out[blk * RPB + (t - 1) * BM + tid] = a;
        }

        // ---- swapped MFMA over wave's 32 rows x 64 n + epilogue ----
        #pragma unroll
        for (int mi = 0; mi < 2; ++mi) {
            const int rr = 32 * wr + 16 * mi + lo;
            const unsigned swr = (unsigned)((rr & 7) << 4);
            f16x8 af[4];
            #pragma unroll
            for (int ki = 0; ki < 4; ++ki) {
                unsigned off = ((unsigned)(64 * ki + 16 * hi)) ^ swr;
                af[ki] = *(const f16x8*)(Ab + rr * 256 + off);
            }
            f32x4 acc0 = b1v[0], acc1 = b1v[1], acc2 = b1v[2], acc3 = b1v[3];
            __builtin_amdgcn_s_setprio(1);
            #pragma unroll
            for (int ki = 0; ki < 4; ++ki) {
                acc0 = __builtin_amdgcn_mfma_f32_16x16x32_f16(wfrag[ki][0], af[ki], acc0, 0, 0, 0);
                acc1 = __builtin_amdgcn_mfma_f32_16x16x32_f16(wfrag[ki][1], af[ki], acc1, 0, 0, 0);
                acc2 = __builtin_amdgcn_mfma_f32_16x16x32_f16(wfrag[ki][2], af[ki], acc2, 0, 0, 0);
                acc3 = __builtin_amdgcn_mfma_f32_16x16x32_f16(wfrag[ki][3], af[ki], acc3, 0, 0, 0);
            }
            __builtin_amdgcn_s_setprio(0);
            // lane lo = x-row (32wr+16mi+lo); regs r of acc_ni = n-col 64wc+16ni+4hi+r
            float v = 0.f;
            #define EPI(ACC, NI) \
                v += fmaxf(ACC[0], 0.f) * w2v[NI][0] + fmaxf(ACC[1], 0.f) * w2v[NI][1] \
                   + fmaxf(ACC[2], 0.f) * w2v[NI][2] + fmaxf(ACC[3], 0.f) * w2v[NI][3];
            EPI(acc0, 0) EPI(acc1, 1) EPI(acc2, 2) EPI(acc3, 3)
            #undef EPI
            v += __shfl_xor(v, 16);
            v += __shfl_xor(v, 32);
            if (lane < 16) apart[t & 1][wc][32 * wr + 16 * mi + lane] = v;
        }

        // advance incremental b_loc (row += 64)
        rem += BM;
        if (rem >= H_SZ) { rem -= H_SZ; ++b_loc; }
    }
    __syncthreads();
    if (tid < BM) {   // final tile's reduction
        const float* ap = &apart[(TPB - 1) & 1][0][tid];
        float a = ap[0] + ap[BM] + ap[2 * BM] + ap[3 * BM];
        a_out[blk * RPB + (TPB - 1) * BM + tid] = a;
    }
}

// Finish: per-b masked exp, beta=0.5 power norm, weighted dot, sigmoid
__global__ __launch_bounds__(64) void nais_finish(
    const int* __restrict__ history, const int* __restrict__ target,
    const float* __restrict__ a_in, const float* __restrict__ dotd_in,
    float* __restrict__ out)
{
    const int b    = blockIdx.x;
    const int lane = threadIdx.x;
    const int tgt  = target[b];
    float s1 = 0.f, s2 = 0.f;
    for (int h = lane; h < H_SZ; h += 64) {
        int rg = b * H_SZ + h;
        float e = (history[rg] != tgt) ? __expf(a_in[rg]) : 0.f;
        s1 += e;
        s2 += e * dotd_in[rg];
    }
    #pragma unroll
    for (int o = 1; o < 64; o <<= 1) {
        s1 += __shfl_xor(s1, o);
        s2 += __shfl_xor(s2, o);
    }
    if (lane == 0) {
        float pred = s2 / sqrtf(s1);
        out[b] = 1.f / (1.f + __expf(-pred));
    }
}

extern "C" void kernel_launch(void* const* d_in, const int* in_sizes, int n_in,
                              void* d_out, int out_size, void* d_ws, size_t ws_size,
                              hipStream_t stream) {
    const int*   history = (const int*)d_in[0];
    const int*   target  = (const int*)d_in[1];
    const float* eh      = (const float*)d_in[2];
    const float* et      = (const float*)d_in[3];
    const float* W1      = (const float*)d_in[4];
    const float* b1      = (const float*)d_in[5];
    const float* w2      = (const float*)d_in[6];
    float* out = (float*)d_out;

    char* ws = (char*)d_ws;
    uint4* ehh = (uint4*)ws;                                     // 25.6 MB (f16)
    f16*   w1t = (f16*)(ws + (size_t)100000 * D_SZ * 2);         // 64 KB
    float* a_ws = (float*)(ws + (size_t)100000 * D_SZ * 2 + N_SZ * D_SZ * 2);
    float* dotd_ws = a_ws + ROWS;

    const int n8 = 100000 * D_SZ / 8;
    cvt_eh<<<(n8 + 255) / 256, 256, 0, stream>>>(eh, ehh, n8);
    cvt_w1<<<(N_SZ * D_SZ) / 256, 256, 0, stream>>>(W1, w1t);
    nais_main<<<NBLK, 512, 0, stream>>>(history, target, ehh, et, w1t, b1, w2, a_ws, dotd_ws);
    nais_finish<<<B_SZ, 64, 0, stream>>>(history, target, a_ws, dotd_ws, out);
}

// Round 10
// 101.119 us; speedup vs baseline: 1.2095x; 1.2095x over previous
//
#include <hip/hip_runtime.h>

#define B_SZ   4096
#define H_SZ   200
#define D_SZ   128
#define N_SZ   256
#define ROWS   (B_SZ * H_SZ)      // 819200
#define BM     64
#define TPB    8                  // tiles per block
#define RPB    (BM * TPB)         // 512 rows per block
#define NBLK   (ROWS / RPB)       // 1600

typedef _Float16 f16;
typedef __attribute__((ext_vector_type(2))) _Float16 f16x2;
typedef __attribute__((ext_vector_type(8))) _Float16 f16x8;
typedef __attribute__((ext_vector_type(4))) float f32x4;

union H8 { f16x8 v; f16x2 p[4]; uint4 u; };

__device__ __forceinline__ f16x2 pkrtz(float a, float b) {
    return __builtin_bit_cast(f16x2, __builtin_amdgcn_cvt_pkrtz(a, b));
}

// Kernel 0a: embed_history f32 -> f16 (RTZ pack), 8 elems/thread
__global__ __launch_bounds__(256) void cvt_eh(const float* __restrict__ src,
                                              uint4* __restrict__ dst, int n8) {
    int i = blockIdx.x * 256 + threadIdx.x;
    if (i >= n8) return;
    const f32x4* p = (const f32x4*)src + (size_t)i * 2;
    f32x4 a = p[0], b = p[1];
    uint4 o;
    o.x = __builtin_bit_cast(unsigned, pkrtz(a[0], a[1]));
    o.y = __builtin_bit_cast(unsigned, pkrtz(a[2], a[3]));
    o.z = __builtin_bit_cast(unsigned, pkrtz(b[0], b[1]));
    o.w = __builtin_bit_cast(unsigned, pkrtz(b[2], b[3]));
    dst[i] = o;
}

// Kernel 0b: W1 [128][256] f32 -> W1T/16 [256][128] f16
__global__ __launch_bounds__(256) void cvt_w1(const float* __restrict__ src,
                                              f16* __restrict__ dst) {
    int i = blockIdx.x * 256 + threadIdx.x;   // i = n*128 + d
    int n = i >> 7, d = i & 127;
    dst[i] = (f16)(src[d * N_SZ + n] * 0.0625f);
}

// Main: 512 thr = 8 waves; wave w owns N-cols [32w,32w+32)  (r7 structure, VGPR<=64).
// Software-pipelined: construct(t+1) executes in the SHADOW of MFMA(t),
// between mi=0..1 and mi=2..3, inside the barrier-free region.
__global__ __launch_bounds__(512, 4) void nais_main(
    const int* __restrict__ history, const int* __restrict__ target,
    const uint4* __restrict__ ehh, const float* __restrict__ et,
    const f16* __restrict__ w1t, const float* __restrict__ b1,
    const float* __restrict__ w2,
    float* __restrict__ a_out, float* __restrict__ dotd_out)
{
    __shared__ uint4 AbufV[2][BM * 256 / 16];  // 32 KB swizzled [64][128] f16 x2
    __shared__ float apart[2][8][BM];          // 4 KB
    __shared__ f16   tgt_h[4][D_SZ];           // 1 KB (t * 16, f16)
    __shared__ int   tgt_i[4];

    const int tid  = threadIdx.x;
    const int wid  = tid >> 6;
    const int lane = tid & 63;
    const int lo   = lane & 15;
    const int hi   = lane >> 4;
    const int row  = tid >> 3;
    const int seg  = tid & 7;
    const int blk  = blockIdx.x;
    const int b_base = (blk * RPB) / H_SZ;

    if (tid < 4) {
        int bb = b_base + tid;
        tgt_i[tid] = target[bb < B_SZ ? bb : (B_SZ - 1)];
    }
    __syncthreads();
    if (tid < 256) {   // preload 4 target rows as f16 * 16
        const int r4 = tid >> 6, j = (tid & 63) * 2;
        const float* src = et + (size_t)tgt_i[r4] * D_SZ + j;
        ((f16x2*)tgt_h)[tid] = pkrtz(src[0] * 16.f, src[1] * 16.f);
    }

    // W1T/16 fragments: wave wid owns cols [32*wid, 32*wid+32)
    f16x8 wfrag[4][2];
    #pragma unroll
    for (int ni = 0; ni < 2; ++ni) {
        int n = 32 * wid + 16 * ni + lo;
        #pragma unroll
        for (int ki = 0; ki < 4; ++ki)
            wfrag[ki][ni] = *(const f16x8*)(w1t + (size_t)n * D_SZ + 32 * ki + 8 * hi);
    }
    // b1 / w2 per-lane: n = 32wid + {0,16} + 4hi + r
    const int n0 = 32 * wid + 4 * hi;
    const f32x4 b1a = *(const f32x4*)(b1 + n0);
    const f32x4 b1b = *(const f32x4*)(b1 + n0 + 16);
    const f32x4 w2a = *(const f32x4*)(w2 + n0);
    const f32x4 w2b = *(const f32x4*)(w2 + n0 + 16);

    const int grow0 = blk * RPB + row;
    const int* hrow = history + grow0;
    uint4 hq0, hq1;
    {
        const uint4* p = ehh + (size_t)hrow[0] * 16;
        hq0 = p[seg]; hq1 = p[8 + seg];
    }
    int ih_nxt = hrow[BM];
    int b_loc = grow0 / H_SZ - b_base;
    int rem   = grow0 - (b_loc + b_base) * H_SZ;
    __syncthreads();   // tgt_h ready

    // ---- construct macro: tile tt into buffer Bf (consumes hq0/hq1, b_loc) ----
    #define CONSTRUCT(Bf, GR)                                                     \
    {                                                                             \
        H8 h1, h2, t1, t2, x1, x2;                                                \
        h1.u = hq0; h2.u = hq1;                                                   \
        t1.v = *(const f16x8*)&tgt_h[b_loc][8 * seg];                             \
        t2.v = *(const f16x8*)&tgt_h[b_loc][64 + 8 * seg];                        \
        x1.v = h1.v * t1.v;                                                       \
        x2.v = h2.v * t2.v;                                                       \
        float s = 0.f;                                                            \
        _Pragma("unroll")                                                         \
        for (int j = 0; j < 4; ++j) {                                             \
            s = __builtin_amdgcn_fdot2(h1.p[j], t1.p[j], s, false);               \
            s = __builtin_amdgcn_fdot2(h2.p[j], t2.p[j], s, false);               \
        }                                                                         \
        s += __shfl_xor(s, 1);                                                    \
        s += __shfl_xor(s, 2);                                                    \
        s += __shfl_xor(s, 4);                                                    \
        if (seg == 0) dotd_out[GR] = s * 0.0625f;                                 \
        const unsigned sw_ = (unsigned)((row & 7) << 4);                          \
        char* rb_ = (char*)(Bf) + row * 256;                                      \
        *(uint4*)(rb_ + (((unsigned)(16 * seg)) ^ sw_))          = x1.u;          \
        *(uint4*)(rb_ + (128u + (((unsigned)(16 * seg)) ^ sw_))) = x2.u;          \
    }

    // ---- one 16-row MFMA + epilogue phase ----
    #define MIPHASE(Ab, MI, PAR)                                                  \
    {                                                                             \
        const int rr = 16 * (MI) + lo;                                            \
        const unsigned swr = (unsigned)((rr & 7) << 4);                           \
        f16x8 af[4];                                                              \
        _Pragma("unroll")                                                         \
        for (int ki = 0; ki < 4; ++ki) {                                          \
            unsigned off = ((unsigned)(64 * ki + 16 * hi)) ^ swr;                 \
            af[ki] = *(const f16x8*)((char*)(Ab) + rr * 256 + off);               \
        }                                                                         \
        f32x4 acc0 = b1a, acc1 = b1b;                                             \
        _Pragma("unroll")                                                         \
        for (int ki = 0; ki < 4; ++ki) {                                          \
            acc0 = __builtin_amdgcn_mfma_f32_16x16x32_f16(wfrag[ki][0], af[ki], acc0, 0, 0, 0); \
            acc1 = __builtin_amdgcn_mfma_f32_16x16x32_f16(wfrag[ki][1], af[ki], acc1, 0, 0, 0); \
        }                                                                         \
        float v = fmaxf(acc0[0], 0.f) * w2a[0] + fmaxf(acc1[0], 0.f) * w2b[0];    \
        v += fmaxf(acc0[1], 0.f) * w2a[1] + fmaxf(acc1[1], 0.f) * w2b[1];         \
        v += fmaxf(acc0[2], 0.f) * w2a[2] + fmaxf(acc1[2], 0.f) * w2b[2];         \
        v += fmaxf(acc0[3], 0.f) * w2a[3] + fmaxf(acc1[3], 0.f) * w2b[3];         \
        v += __shfl_xor(v, 16);                                                   \
        v += __shfl_xor(v, 32);                                                   \
        if (lane < 16) apart[PAR][wid][16 * (MI) + lane] = v;                     \
    }

    // prologue: construct tile 0, issue gathers(1)
    CONSTRUCT(AbufV[0], grow0)
    {
        const uint4* p = ehh + (size_t)ih_nxt * 16;
        hq0 = p[seg]; hq1 = p[8 + seg];
    }
    ih_nxt = hrow[2 * BM];
    __syncthreads();   // buf0 ready

    for (int t = 0; t < TPB; ++t) {
        const uint4* Ab = AbufV[t & 1];
        const int par = t & 1;

        MIPHASE(Ab, 0, par)
        MIPHASE(Ab, 1, par)

        // ---- shadow region: construct(t+1), prefetch(t+2), lagged a_out ----
        if (t + 1 < TPB) {
            rem += BM;
            if (rem >= H_SZ) { rem -= H_SZ; ++b_loc; }
            CONSTRUCT(AbufV[(t + 1) & 1], grow0 + (t + 1) * BM)
            if (t + 2 < TPB) {
                const uint4* p = ehh + (size_t)ih_nxt * 16;
                hq0 = p[seg]; hq1 = p[8 + seg];
            }
            if (t + 3 < TPB) ih_nxt = hrow[(t + 3) * BM];
        }
        if (t > 0 && tid < BM) {
            const float* ap = &apart[(t - 1) & 1][0][tid];
            float a = ap[0];
            #pragma unroll
            for (int w = 1; w < 8; ++w) a += ap[w * BM];
            a_out[blk * RPB + (t - 1) * BM + tid] = a;
        }

        MIPHASE(Ab, 2, par)
        MIPHASE(Ab, 3, par)

        __syncthreads();
    }
    if (tid < BM) {   // final tile's reduction
        const float* ap = &apart[(TPB - 1) & 1][0][tid];
        float a = ap[0];
        #pragma unroll
        for (int w = 1; w < 8; ++w) a += ap[w * BM];
        a_out[blk * RPB + (TPB - 1) * BM + tid] = a;
    }
    #undef CONSTRUCT
    #undef MIPHASE
}

// Finish: per-b masked exp, beta=0.5 power norm, weighted dot, sigmoid
__global__ __launch_bounds__(64) void nais_finish(
    const int* __restrict__ history, const int* __restrict__ target,
    const float* __restrict__ a_in, const float* __restrict__ dotd_in,
    float* __restrict__ out)
{
    const int b    = blockIdx.x;
    const int lane = threadIdx.x;
    const int tgt  = target[b];
    float s1 = 0.f, s2 = 0.f;
    for (int h = lane; h < H_SZ; h += 64) {
        int rg = b * H_SZ + h;
        float e = (history[rg] != tgt) ? __expf(a_in[rg]) : 0.f;
        s1 += e;
        s2 += e * dotd_in[rg];
    }
    #pragma unroll
    for (int o = 1; o < 64; o <<= 1) {
        s1 += __shfl_xor(s1, o);
        s2 += __shfl_xor(s2, o);
    }
    if (lane == 0) {
        float pred = s2 / sqrtf(s1);
        out[b] = 1.f / (1.f + __expf(-pred));
    }
}

extern "C" void kernel_launch(void* const* d_in, const int* in_sizes, int n_in,
                              void* d_out, int out_size, void* d_ws, size_t ws_size,
                              hipStream_t stream) {
    const int*   history = (const int*)d_in[0];
    const int*   target  = (const int*)d_in[1];
    const float* eh      = (const float*)d_in[2];
    const float* et      = (const float*)d_in[3];
    const float* W1      = (const float*)d_in[4];
    const float* b1      = (const float*)d_in[5];
    const float* w2      = (const float*)d_in[6];
    float* out = (float*)d_out;

    char* ws = (char*)d_ws;
    uint4* ehh = (uint4*)ws;                                     // 25.6 MB (f16)
    f16*   w1t = (f16*)(ws + (size_t)100000 * D_SZ * 2);         // 64 KB
    float* a_ws = (float*)(ws + (size_t)100000 * D_SZ * 2 + N_SZ * D_SZ * 2);
    float* dotd_ws = a_ws + ROWS;

    const int n8 = 100000 * D_SZ / 8;
    cvt_eh<<<(n8 + 255) / 256, 256, 0, stream>>>(eh, ehh, n8);
    cvt_w1<<<(N_SZ * D_SZ) / 256, 256, 0, stream>>>(W1, w1t);
    nais_main<<<NBLK, 512, 0, stream>>>(history, target, ehh, et, w1t, b1, w2, a_ws, dotd_ws);
    nais_finish<<<B_SZ, 64, 0, stream>>>(history, target, a_ws, dotd_ws, out);
}